// Round 1
// baseline (767.288 us; speedup 1.0000x reference)
//
#include <hip/hip_runtime.h>
#include <stdint.h>

#define BN_EPS 1e-5f

static __device__ __forceinline__ uint32_t bf16bits(float f){
  uint32_t u = __float_as_uint(f);
  return (u + 0x7fffu + ((u>>16)&1u)) >> 16;
}
static __device__ __forceinline__ float bf16tof(uint32_t us){
  return __uint_as_float(us<<16);
}

// ---------- tiny per-call weight precompute ----------
// a1[c], b1[c]: fold Linear(1,256)+BN1 into per-channel affine of scalar s
// c12 = b1b @ w2a ; A2/B2: fold BN2 (+b2a) into per-channel affine
__global__ void prep_small(const float* __restrict__ w1a, const float* __restrict__ b1a,
                           const float* __restrict__ g1,  const float* __restrict__ be1,
                           const float* __restrict__ m1,  const float* __restrict__ v1,
                           const float* __restrict__ b1b, const float* __restrict__ w2a,
                           const float* __restrict__ b2a, const float* __restrict__ g2,
                           const float* __restrict__ be2, const float* __restrict__ m2,
                           const float* __restrict__ v2,
                           float* __restrict__ a1, float* __restrict__ b1v,
                           float* __restrict__ c12, float* __restrict__ A2, float* __restrict__ B2){
  int c = threadIdx.x;
  float s1 = g1[c] * rsqrtf(v1[c] + BN_EPS);
  a1[c]  = w1a[c] * s1;
  b1v[c] = (b1a[c] - m1[c]) * s1 + be1[c];
  if (c < 64){
    float acc = 0.f;
    for (int d = 0; d < 128; ++d) acc = fmaf(b1b[d], w2a[d*64 + c], acc);
    c12[c] = acc;
    float s2 = g2[c] * rsqrtf(v2[c] + BN_EPS);
    A2[c] = s2;
    B2[c] = (b2a[c] - m2[c]) * s2 + be2[c];
  }
}

// W12 = w1b[256,128] @ w2a[128,64]
__global__ void prep_w12(const float* __restrict__ w1b, const float* __restrict__ w2a,
                         float* __restrict__ W12){
  int idx = blockIdx.x*256 + threadIdx.x;   // 16384 threads
  int c = idx >> 6, k = idx & 63;
  float acc = 0.f;
  for (int d = 0; d < 128; ++d) acc = fmaf(w1b[c*128 + d], w2a[d*64 + k], acc);
  W12[idx] = acc;
}

// ---------- CSR build (dst -> list of src) ----------
__global__ __launch_bounds__(256) void count_deg(const int* __restrict__ ei, int* __restrict__ cnt, int E){
  int i = blockIdx.x*256 + threadIdx.x;
  if (i < E) atomicAdd(&cnt[ei[E + i]], 1);   // dst row
}

__global__ __launch_bounds__(256) void scan_a(const int* __restrict__ cnt, int* __restrict__ rowstart,
                                              int* __restrict__ bsums, int n){
  __shared__ int sm[256];
  int i = blockIdx.x*256 + threadIdx.x;
  int t = threadIdx.x;
  int v = (i < n) ? cnt[i] : 0;
  sm[t] = v; __syncthreads();
  for (int off = 1; off < 256; off <<= 1){
    int xv = (t >= off) ? sm[t-off] : 0;
    __syncthreads();
    sm[t] += xv; __syncthreads();
  }
  if (i < n) rowstart[i+1] = sm[t];
  if (t == 255) bsums[blockIdx.x] = sm[255];
}

__global__ __launch_bounds__(512) void scan_b(int* __restrict__ bsums, int nb){
  __shared__ int sm[512];
  int t = threadIdx.x;
  int v = (t < nb) ? bsums[t] : 0;
  sm[t] = v; __syncthreads();
  for (int off = 1; off < 512; off <<= 1){
    int xv = (t >= off) ? sm[t-off] : 0;
    __syncthreads();
    sm[t] += xv; __syncthreads();
  }
  if (t < nb) bsums[t] = sm[t] - v;   // exclusive
}

__global__ __launch_bounds__(256) void scan_c(int* __restrict__ rowstart, const int* __restrict__ bsums, int n){
  int i = blockIdx.x*256 + threadIdx.x;
  if (i < n) rowstart[i+1] += bsums[blockIdx.x];
  if (i == 0) rowstart[0] = 0;
}

__global__ __launch_bounds__(256) void init_pos(const int* __restrict__ rowstart, int* __restrict__ pos, int n){
  int i = blockIdx.x*256 + threadIdx.x;
  if (i < n) pos[i] = rowstart[i];
}

__global__ __launch_bounds__(256) void fill_csr(const int* __restrict__ ei, int* __restrict__ pos,
                                                int* __restrict__ col, int E){
  int i = blockIdx.x*256 + threadIdx.x;
  if (i < E){
    int d = ei[E + i];
    int s = ei[i];
    int slot = atomicAdd(&pos[d], 1);
    col[slot] = s;
  }
}

// ---------- fused GIN layer 1 + Linear(128->64) of mlp2 ----------
// per node: s = x_i + sum_j x_j ; t[k] = sum_c ReLU(a1[c]*s+b1[c]) * W12[c][k] + c12[k]
__global__ __launch_bounds__(256) void gin1_fused(const float* __restrict__ x,
    const int* __restrict__ rowstart, const int* __restrict__ col,
    const float* __restrict__ a1, const float* __restrict__ b1v,
    const float* __restrict__ W12, const float* __restrict__ c12,
    unsigned short* __restrict__ t, int n){
  int i = blockIdx.x*256 + threadIdx.x;
  if (i >= n) return;
  float s = x[i];
  int beg = rowstart[i], end = rowstart[i+1];
  for (int j = beg; j < end; ++j) s += x[col[j]];
  float acc[64];
  #pragma unroll
  for (int k = 0; k < 64; ++k) acc[k] = c12[k];
  for (int c = 0; c < 256; ++c){
    float r = fmaf(a1[c], s, b1v[c]);
    r = fmaxf(r, 0.f);
    const float* wr = W12 + c*64;           // wave-uniform -> s_load
    #pragma unroll
    for (int k = 0; k < 64; ++k) acc[k] = fmaf(r, wr[k], acc[k]);
  }
  uint4* dst = reinterpret_cast<uint4*>(t + (size_t)i*64);
  #pragma unroll
  for (int q = 0; q < 8; ++q){
    uint4 v;
    v.x = bf16bits(acc[q*8+0]) | (bf16bits(acc[q*8+1])<<16);
    v.y = bf16bits(acc[q*8+2]) | (bf16bits(acc[q*8+3])<<16);
    v.z = bf16bits(acc[q*8+4]) | (bf16bits(acc[q*8+5])<<16);
    v.w = bf16bits(acc[q*8+6]) | (bf16bits(acc[q*8+7])<<16);
    dst[q] = v;
  }
}

// ---------- GIN layer 2 aggregation + BN2 + ReLU ----------
// wave per node, lane = channel; r2[i][c] = ReLU((t_i + sum_j t_j)[c]*A2[c] + B2[c])
__global__ __launch_bounds__(256) void gin2_agg(const unsigned short* __restrict__ t,
    const int* __restrict__ rowstart, const int* __restrict__ col,
    const float* __restrict__ A2, const float* __restrict__ B2,
    float* __restrict__ r2, int n){
  int gid = blockIdx.x*256 + threadIdx.x;
  int w = gid >> 6;
  int lane = threadIdx.x & 63;
  if (w >= n) return;
  float acc = bf16tof(t[(size_t)w*64 + lane]);   // self term
  int beg = rowstart[w], end = rowstart[w+1];
  int j = beg;
  for (; j + 3 < end; j += 4){
    int c0 = col[j], c1 = col[j+1], c2 = col[j+2], c3 = col[j+3];
    float f0 = bf16tof(t[(size_t)c0*64 + lane]);
    float f1 = bf16tof(t[(size_t)c1*64 + lane]);
    float f2 = bf16tof(t[(size_t)c2*64 + lane]);
    float f3 = bf16tof(t[(size_t)c3*64 + lane]);
    acc += (f0 + f1) + (f2 + f3);
  }
  for (; j < end; ++j) acc += bf16tof(t[(size_t)col[j]*64 + lane]);
  float val = fmaf(acc, A2[lane], B2[lane]);
  r2[(size_t)w*64 + lane] = fmaxf(val, 0.f);
}

// ---------- Linear(64,64) of mlp2 + head + log_softmax ----------
__global__ __launch_bounds__(256) void head_kernel(const float* __restrict__ r2,
    const float* __restrict__ w2b, const float* __restrict__ b2b,
    const float* __restrict__ wl1, const float* __restrict__ bl1,
    const float* __restrict__ wl2, const float* __restrict__ bl2,
    float* __restrict__ out, int n){
  int i = blockIdx.x*256 + threadIdx.x;
  if (i >= n) return;
  float h[64];
  #pragma unroll
  for (int k = 0; k < 64; ++k) h[k] = b2b[k];
  const float4* rr = reinterpret_cast<const float4*>(r2 + (size_t)i*64);
  for (int cq = 0; cq < 16; ++cq){
    float4 rv = rr[cq];
    float re[4] = {rv.x, rv.y, rv.z, rv.w};
    #pragma unroll
    for (int e = 0; e < 4; ++e){
      float rc = re[e];
      const float* wr = w2b + (cq*4 + e)*64;  // wave-uniform -> s_load
      #pragma unroll
      for (int k = 0; k < 64; ++k) h[k] = fmaf(rc, wr[k], h[k]);
    }
  }
  float z[16];
  #pragma unroll
  for (int jj = 0; jj < 16; ++jj) z[jj] = bl1[jj];
  #pragma unroll
  for (int k = 0; k < 64; ++k){
    float hk = h[k];
    const float* wr = wl1 + k*16;
    #pragma unroll
    for (int jj = 0; jj < 16; ++jj) z[jj] = fmaf(hk, wr[jj], z[jj]);
  }
  float lg[6];
  #pragma unroll
  for (int l = 0; l < 6; ++l) lg[l] = bl2[l];
  #pragma unroll
  for (int jj = 0; jj < 16; ++jj){
    float zj = fmaxf(z[jj], 0.f);
    const float* wr = wl2 + jj*6;
    #pragma unroll
    for (int l = 0; l < 6; ++l) lg[l] = fmaf(zj, wr[l], lg[l]);
  }
  float m = lg[0];
  #pragma unroll
  for (int l = 1; l < 6; ++l) m = fmaxf(m, lg[l]);
  float sum = 0.f;
  #pragma unroll
  for (int l = 0; l < 6; ++l) sum += expf(lg[l] - m);
  float lse = m + logf(sum);
  float* op = out + (size_t)i*6;
  #pragma unroll
  for (int l = 0; l < 6; ++l) op[l] = lg[l] - lse;
}

extern "C" void kernel_launch(void* const* d_in, const int* in_sizes, int n_in,
                              void* d_out, int out_size, void* d_ws, size_t ws_size,
                              hipStream_t stream){
  const float* x   = (const float*)d_in[0];
  const int*   ei  = (const int*)d_in[1];
  const float* w1a = (const float*)d_in[2];
  const float* b1a = (const float*)d_in[3];
  const float* g1  = (const float*)d_in[4];
  const float* be1 = (const float*)d_in[5];
  const float* m1  = (const float*)d_in[6];
  const float* v1  = (const float*)d_in[7];
  const float* w1b = (const float*)d_in[8];
  const float* b1b = (const float*)d_in[9];
  const float* w2a = (const float*)d_in[10];
  const float* b2a = (const float*)d_in[11];
  const float* g2  = (const float*)d_in[12];
  const float* be2 = (const float*)d_in[13];
  const float* m2  = (const float*)d_in[14];
  const float* v2  = (const float*)d_in[15];
  const float* w2b = (const float*)d_in[16];
  const float* b2b = (const float*)d_in[17];
  const float* wl1 = (const float*)d_in[18];
  const float* bl1 = (const float*)d_in[19];
  const float* wl2 = (const float*)d_in[20];
  const float* bl2 = (const float*)d_in[21];
  float* out = (float*)d_out;
  int n = in_sizes[0];        // N (x is [N,1])
  int E = in_sizes[1] / 2;    // edge_index is [2,E]

  char* ws = (char*)d_ws;
  size_t off = 0;
  auto carve = [&](size_t bytes)->char*{ char* p = ws + off; off += (bytes + 255) & ~(size_t)255; return p; };
  float* a1   = (float*)carve(256*4);
  float* b1v  = (float*)carve(256*4);
  float* c12  = (float*)carve(64*4);
  float* A2   = (float*)carve(64*4);
  float* B2   = (float*)carve(64*4);
  float* W12  = (float*)carve(16384*4);
  int* rowstart = (int*)carve((size_t)(n+1)*4);
  int* pos    = (int*)carve((size_t)n*4);
  int* bsums  = (int*)carve(512*4);
  int* col    = (int*)carve((size_t)E*4);
  unsigned short* t = (unsigned short*)carve((size_t)n*64*2);
  float* r2   = (float*)carve((size_t)n*64*4);

  int nb = (n + 255) / 256;

  hipMemsetAsync(pos, 0, (size_t)n*4, stream);
  prep_small<<<1, 256, 0, stream>>>(w1a,b1a,g1,be1,m1,v1,b1b,w2a,b2a,g2,be2,m2,v2,a1,b1v,c12,A2,B2);
  prep_w12<<<64, 256, 0, stream>>>(w1b, w2a, W12);
  count_deg<<<(E+255)/256, 256, 0, stream>>>(ei, pos, E);
  scan_a<<<nb, 256, 0, stream>>>(pos, rowstart, bsums, n);
  scan_b<<<1, 512, 0, stream>>>(bsums, nb);
  scan_c<<<nb, 256, 0, stream>>>(rowstart, bsums, n);
  init_pos<<<nb, 256, 0, stream>>>(rowstart, pos, n);
  fill_csr<<<(E+255)/256, 256, 0, stream>>>(ei, pos, col, E);
  gin1_fused<<<nb, 256, 0, stream>>>(x, rowstart, col, a1, b1v, W12, c12, t, n);
  gin2_agg<<<(int)(((size_t)n*64 + 255)/256), 256, 0, stream>>>(t, rowstart, col, A2, B2, r2, n);
  head_kernel<<<nb, 256, 0, stream>>>(r2, w2b, b2b, wl1, bl1, wl2, bl2, out, n);
}